// Round 10
// baseline (51.227 us; speedup 1.0000x reference)
//
#include <hip/hip_runtime.h>
#include <cstdint>
#include <cstddef>

#define B_ 4
#define N_ 16384
#define M_ 2048
#define C_ 64
#define S_ 32
#define J_ 67          // 3 + C
#define R2_ 0.04f
#define EPS_ 1e-5f

typedef float f32x4 __attribute__((ext_vector_type(4)));  // clang vector type

// ---------------------------------------------------------------------------
// KA: fused independent phases.
//   blocks [0, 8192):    ball-query scan, one center per block (4 waves)
//   blocks [8192, 9216): transpose features (B,C,N) -> featT (B,N,C)
// Scan first: its long-tail blocks (sparse centers, 8-16 rounds) drain while
// the transpose blocks back-fill the CUs at the end of the dispatch.
// ---------------------------------------------------------------------------
__global__ __launch_bounds__(256) void k_phase1(
        const float* __restrict__ feat, float* __restrict__ featT,
        const float* __restrict__ pts, const float* __restrict__ ctr,
        int* __restrict__ idx_ws) {
    __shared__ float tile[64][65];            // transpose tile (16.6 KB)
    int blk = blockIdx.x;
    int tid = threadIdx.x;

    if (blk >= 8192) {
        // ---- transpose role ----
        int ti = blk - 8192;                  // 0..1023
        int b  = ti >> 8;                     // N_/64 = 256 tiles per batch
        int n0 = (ti & 255) << 6;
        int r = tid >> 6, i = tid & 63;
        const float* fb = feat + (size_t)b * C_ * N_;
        #pragma unroll
        for (int cc = r; cc < 64; cc += 4)    // read-once: nontemporal
            tile[cc][i] = __builtin_nontemporal_load(&fb[(size_t)cc * N_ + n0 + i]);
        __syncthreads();
        float* ftb = featT + (size_t)b * N_ * C_;
        #pragma unroll
        for (int nn = r; nn < 64; nn += 4)
            ftb[(size_t)(n0 + nn) * C_ + i] = tile[i][nn];  // re-read: keep cached
        return;
    }

    // ---- ball-query scan role: one center per block, 4 waves ----
    __shared__ int wcnt[4];                   // per-wave in-chunk count (round)
    __shared__ int widx[4][S_];               // per-wave first-32 chunk indices
    __shared__ int result[S_];                // combined first-32 (ascending)
    int w    = tid >> 6;
    int lane = tid & 63;
    int bm   = blk;                           // 0..8191
    int b    = bm >> 11;                      // M_ = 2048
    const float3* pb3 = (const float3*)(pts + (size_t)b * N_ * 3);
    float cx = ctr[(size_t)bm * 3 + 0];
    float cy = ctr[(size_t)bm * 3 + 1];
    float cz = ctr[(size_t)bm * 3 + 2];

    float3 cur[4], nxtv[4];
    #pragma unroll
    for (int r = 0; r < 4; r++)               // round 0 chunk loads (dwordx3)
        cur[r] = pb3[w * 256 + r * 64 + lane];
    int total = 0;
    for (int base = 0; base < N_; base += 1024) {
        int nb = base + 1024;
        if (nb < N_) {
            #pragma unroll
            for (int r = 0; r < 4; r++)       // prefetch next round's chunk
                nxtv[r] = pb3[nb + w * 256 + r * 64 + lane];
        }
        int cbase = base + w * 256;
        int cnt = 0;                          // within-chunk count
        #pragma unroll
        for (int r = 0; r < 4; r++) {
            // bit-exact vs numpy: no FMA contraction, (x^2 + y^2) + z^2 order
            float dx = __fsub_rn(cx, cur[r].x);
            float dy = __fsub_rn(cy, cur[r].y);
            float dz = __fsub_rn(cz, cur[r].z);
            float d2 = __fadd_rn(__fadd_rn(__fmul_rn(dx, dx), __fmul_rn(dy, dy)),
                                 __fmul_rn(dz, dz));
            bool in = d2 < R2_;               // MIN_RADIUS=0: lower bound always true
            unsigned long long mk = __ballot(in);
            int rank = __popcll(mk & ((1ull << lane) - 1ull));
            int pos = cnt + rank;
            if (in && pos < S_) widx[w][pos] = cbase + r * 64 + lane;
            cnt += __popcll(mk);
        }
        if (lane == 0) wcnt[w] = cnt;
        __syncthreads();                      // wcnt/widx visible to all
        int c0 = wcnt[0], c1 = wcnt[1], c2 = wcnt[2], c3 = wcnt[3];
        int offw = total + ((w > 0) ? c0 : 0) + ((w > 1) ? c1 : 0) + ((w > 2) ? c2 : 0);
        int cw = wcnt[w] < S_ ? wcnt[w] : S_;
        if (lane < cw) {                      // concat wave segments, chunk order
            int dst = offw + lane;
            if (dst < S_) result[dst] = widx[w][lane];
        }
        __syncthreads();                      // result stable; widx reusable
        total += c0 + c1 + c2 + c3;
        if (total >= S_ || nb >= N_) break;   // block-uniform
        #pragma unroll
        for (int r = 0; r < 4; r++) cur[r] = nxtv[r];
    }
    int cfound = total < S_ ? total : S_;
    if (tid < S_) {
        int first = (cfound > 0) ? result[0] : 0;       // empty ball -> zeros
        int v = (tid < cfound) ? result[tid] : first;
        idx_ws[(size_t)bm * S_ + tid] = v;              // padded idx (ref semantics)
    }
}

// ---------------------------------------------------------------------------
// KB: per-center partial sums, ONE CENTER PER WAVE (4/block, 2048 blocks) —
// max TLP for the gather-latency phase. Reassociated — feeds scalar std only.
// ---------------------------------------------------------------------------
__global__ __launch_bounds__(256) void k_sums(
        const float* __restrict__ pts, const float* __restrict__ ctr,
        const float* __restrict__ featT, const float* __restrict__ cfeat,
        const int* __restrict__ idx_ws, float* __restrict__ bpart) {
    __shared__ float pp1[4], pp2[4];
    int w    = threadIdx.x >> 6;
    int lane = threadIdx.x & 63;
    int bm   = blockIdx.x * 4 + w;
    int b    = bm >> 11;
    const float3* pb3 = (const float3*)(pts + (size_t)b * N_ * 3);
    const float* ftb = featT + (size_t)b * N_ * C_;
    int id = idx_ws[(size_t)bm * S_ + (lane & 31)];
    float cf = cfeat[(size_t)bm * C_ + lane];
    float cx = ctr[(size_t)bm * 3 + 0];
    float cy = ctr[(size_t)bm * 3 + 1];
    float cz = ctr[(size_t)bm * 3 + 2];

    float s1 = 0.f, s2 = 0.f;
    float v[S_];
    #pragma unroll
    for (int s = 0; s < S_; s++) {            // 32 independent coalesced row loads
        int p = __shfl(id, s);
        v[s] = ftb[(size_t)p * C_ + lane];
    }
    #pragma unroll
    for (int s = 0; s < S_; s++) { float d = v[s] - cf; s1 += d; s2 += d * d; }
    float3 q = pb3[id];                       // one dwordx3 gather per lane
    float cj = (lane < 32) ? cx : cy;         // xyz spread across half-waves
    float pv = (lane < 32) ? q.x : q.y;
    float d0 = pv - cj; s1 += d0; s2 += d0 * d0;
    if (lane < 32) { float dz = q.z - cz; s1 += dz; s2 += dz * dz; }
    #pragma unroll
    for (int off = 32; off > 0; off >>= 1) {
        s1 += __shfl_down(s1, off);
        s2 += __shfl_down(s2, off);
    }
    if (lane == 0) { pp1[w] = s1; pp2[w] = s2; }
    __syncthreads();
    if (threadIdx.x == 0) {                   // fixed-order block combine
        bpart[blockIdx.x * 2 + 0] = ((pp1[0] + pp1[1]) + pp1[2]) + pp1[3];
        bpart[blockIdx.x * 2 + 1] = ((pp2[0] + pp2[1]) + pp2[2]) + pp2[3];
    }
}

// ---------------------------------------------------------------------------
// K3: inline per-batch std reduce (512 partials: pairwise then 256-tree,
// identical order in every block) + output (B,67,M,S), nontemporal f32x4
// stores. 2048 blocks, 4 m's/block: thread = (mi=tid>>6, cg=(tid>>3)&7,
// sq=tid&7); each cg covers 8 channels (2 cq); cg 0 adds xyz.
// ---------------------------------------------------------------------------
__global__ __launch_bounds__(256) void k_output(
        const float* __restrict__ pts, const float* __restrict__ ctr,
        const float* __restrict__ featT, const float* __restrict__ cfeat,
        const float* __restrict__ alpha, const float* __restrict__ beta,
        const int* __restrict__ idx_ws, const float* __restrict__ bpart,
        float* __restrict__ out) {
    __shared__ float r1[256], r2[256];
    int blk = blockIdx.x, tid = threadIdx.x;
    int batch = blk >> 9;                     // 512 blocks per batch

    // --- per-batch std: 512 partials -> pairwise -> 256-entry tree ---
    const float* bp = bpart + (size_t)batch * 512 * 2;
    r1[tid] = bp[tid * 2 + 0] + bp[(tid + 256) * 2 + 0];
    r2[tid] = bp[tid * 2 + 1] + bp[(tid + 256) * 2 + 1];
    __syncthreads();
    for (int off = 128; off > 0; off >>= 1) {
        if (tid < off) { r1[tid] += r1[tid + off]; r2[tid] += r2[tid + off]; }
        __syncthreads();
    }
    float sum = r1[0], sumsq = r2[0];
    const float n = (float)(M_ * S_ * J_);            // 4390912 < 2^24, exact
    float mean = sum / n;
    float var  = (sumsq - sum * mean) / (n - 1.f);    // ddof = 1
    float inv  = 1.f / (sqrtf(var) + EPS_);

    // --- output: 4 m's per block ---
    int mi = tid >> 6;                        // 0..3
    int cg = (tid >> 3) & 7;                  // channel group: 8 channels each
    int sq = tid & 7;                         // s-quad
    int m  = (blk & 511) * 4 + mi;
    int s0 = sq * 4;
    size_t bm = (size_t)batch * M_ + m;
    int4 pidx = *(const int4*)(idx_ws + bm * S_ + s0);
    size_t obase = ((size_t)batch * J_ * M_ + m) * (size_t)S_ + s0;

    if (cg == 0) {                            // xyz rows: dwordx3 gathers
        const float3* pb3 = (const float3*)(pts + (size_t)batch * N_ * 3);
        float3 q0 = pb3[pidx.x], q1 = pb3[pidx.y], q2 = pb3[pidx.z], q3 = pb3[pidx.w];
        float3 cj3;
        cj3.x = ctr[bm * 3 + 0]; cj3.y = ctr[bm * 3 + 1]; cj3.z = ctr[bm * 3 + 2];
        {
            float a = alpha[0] * inv, bt = beta[0];
            f32x4 o = { a * (q0.x - cj3.x) + bt, a * (q1.x - cj3.x) + bt,
                        a * (q2.x - cj3.x) + bt, a * (q3.x - cj3.x) + bt };
            __builtin_nontemporal_store(o, (f32x4*)(out + obase + (size_t)0 * (M_ * S_)));
        }
        {
            float a = alpha[1] * inv, bt = beta[1];
            f32x4 o = { a * (q0.y - cj3.y) + bt, a * (q1.y - cj3.y) + bt,
                        a * (q2.y - cj3.y) + bt, a * (q3.y - cj3.y) + bt };
            __builtin_nontemporal_store(o, (f32x4*)(out + obase + (size_t)1 * (M_ * S_)));
        }
        {
            float a = alpha[2] * inv, bt = beta[2];
            f32x4 o = { a * (q0.z - cj3.z) + bt, a * (q1.z - cj3.z) + bt,
                        a * (q2.z - cj3.z) + bt, a * (q3.z - cj3.z) + bt };
            __builtin_nontemporal_store(o, (f32x4*)(out + obase + (size_t)2 * (M_ * S_)));
        }
    }
    const float4* f0 = (const float4*)(featT + ((size_t)batch * N_ + pidx.x) * C_);
    const float4* f1 = (const float4*)(featT + ((size_t)batch * N_ + pidx.y) * C_);
    const float4* f2 = (const float4*)(featT + ((size_t)batch * N_ + pidx.z) * C_);
    const float4* f3 = (const float4*)(featT + ((size_t)batch * N_ + pidx.w) * C_);
    const float4* cf = (const float4*)(cfeat + bm * C_);
    #pragma unroll
    for (int cq = cg * 2; cq < cg * 2 + 2; cq++) {
        float4 v0 = f0[cq], v1 = f1[cq], v2 = f2[cq], v3 = f3[cq], c = cf[cq];
        int j = 3 + cq * 4;
        float a0 = alpha[j + 0] * inv, b0 = beta[j + 0];
        float a1 = alpha[j + 1] * inv, b1 = beta[j + 1];
        float a2 = alpha[j + 2] * inv, b2 = beta[j + 2];
        float a3 = alpha[j + 3] * inv, b3 = beta[j + 3];
        f32x4 o0, o1, o2, o3;                 // transpose 4x4 block in regs
        o0.x = a0 * (v0.x - c.x) + b0; o0.y = a0 * (v1.x - c.x) + b0;
        o0.z = a0 * (v2.x - c.x) + b0; o0.w = a0 * (v3.x - c.x) + b0;
        o1.x = a1 * (v0.y - c.y) + b1; o1.y = a1 * (v1.y - c.y) + b1;
        o1.z = a1 * (v2.y - c.y) + b1; o1.w = a1 * (v3.y - c.y) + b1;
        o2.x = a2 * (v0.z - c.z) + b2; o2.y = a2 * (v1.z - c.z) + b2;
        o2.z = a2 * (v2.z - c.z) + b2; o2.w = a2 * (v3.z - c.z) + b2;
        o3.x = a3 * (v0.w - c.w) + b3; o3.y = a3 * (v1.w - c.w) + b3;
        o3.z = a3 * (v2.w - c.w) + b3; o3.w = a3 * (v3.w - c.w) + b3;
        __builtin_nontemporal_store(o0, (f32x4*)(out + obase + (size_t)(j + 0) * (M_ * S_)));
        __builtin_nontemporal_store(o1, (f32x4*)(out + obase + (size_t)(j + 1) * (M_ * S_)));
        __builtin_nontemporal_store(o2, (f32x4*)(out + obase + (size_t)(j + 2) * (M_ * S_)));
        __builtin_nontemporal_store(o3, (f32x4*)(out + obase + (size_t)(j + 3) * (M_ * S_)));
    }
}

// ---------------------------------------------------------------------------
extern "C" void kernel_launch(void* const* d_in, const int* in_sizes, int n_in,
                              void* d_out, int out_size, void* d_ws, size_t ws_size,
                              hipStream_t stream) {
    const float* pts   = (const float*)d_in[0];   // (B,N,3)
    const float* ctr   = (const float*)d_in[1];   // (B,M,3)
    const float* cfeat = (const float*)d_in[2];   // (B,M,C)
    const float* feat  = (const float*)d_in[3];   // (B,C,N)
    const float* alpha = (const float*)d_in[4];   // (67)
    const float* beta  = (const float*)d_in[5];   // (67)
    float* out = (float*)d_out;

    // ws: featT 16 MB | idx 1 MB | bpart 16 KB
    char* ws = (char*)d_ws;
    float* featT = (float*)ws;
    int*   idx_ws = (int*)(ws + (size_t)B_ * N_ * C_ * 4);
    float* bpart = (float*)(ws + (size_t)B_ * N_ * C_ * 4 + (size_t)B_ * M_ * S_ * 4);

    k_phase1<<<8192 + 1024, 256, 0, stream>>>(feat, featT, pts, ctr, idx_ws);
    k_sums<<<2048, 256, 0, stream>>>(pts, ctr, featT, cfeat, idx_ws, bpart);
    k_output<<<2048, 256, 0, stream>>>(pts, ctr, featT, cfeat, alpha, beta,
                                       idx_ws, bpart, out);
}